// Round 6
// baseline (118.782 us; speedup 1.0000x reference)
//
#include <hip/hip_runtime.h>
#include <hip/hip_bf16.h>

typedef unsigned short ushort_t;
typedef __attribute__((ext_vector_type(8))) short bf16x8;
typedef __attribute__((ext_vector_type(4))) float f32x4;

// Problem constants
#define NROWS 16384          // B*T
#define FDIM  512            // K
#define GE    640            // G*E
#define EDIM  320
#define DDIM  384
#define CB_OFF 12582912      // 16384*768
#define SCAL_OFF 23068672    // CB_OFF + 16384*640
// bf16 staging inside out[quantized region] (free until vq_rows)
#define XB_OFF 0             // 8388608 bf16 = 4194304 floats
#define WB_OFF 4194304       // floats; 327680 bf16 = 163840 floats

// ---------------- init accumulators ----------------
__global__ void vq_init_k(float* acc, int n) {
    int i = blockIdx.x * 256 + threadIdx.x;
    if (i < n) acc[i] = 0.0f;
}

// ---------------- fp32 -> bf16 convert (RNE) ----------------
static __device__ __forceinline__ unsigned f2bf(float f) {
    unsigned u = __float_as_uint(f);
    return (u + 0x7FFFu + ((u >> 16) & 1u)) >> 16;
}

__global__ __launch_bounds__(256) void convert_bf16_k(
    const float* __restrict__ X, const float* __restrict__ W,
    ushort_t* __restrict__ Xb, ushort_t* __restrict__ Wb)
{
    const size_t i = (size_t)blockIdx.x * 256 + threadIdx.x;
    const float4* src;
    ushort_t* dst;
    if (i < 1048576) {                    // X: 8388608 elems / 8
        src = (const float4*)X + i * 2;
        dst = Xb + i * 8;
    } else {                              // W: 327680 elems / 8
        const size_t j = i - 1048576;
        src = (const float4*)W + j * 2;
        dst = Wb + j * 8;
    }
    const float4 v0 = src[0], v1 = src[1];
    uint4 o;
    o.x = f2bf(v0.x) | (f2bf(v0.y) << 16);
    o.y = f2bf(v0.z) | (f2bf(v0.w) << 16);
    o.z = f2bf(v1.x) | (f2bf(v1.y) << 16);
    o.w = f2bf(v1.z) | (f2bf(v1.w) << 16);
    *(uint4*)dst = o;
}

// ---------------- async global->LDS helper ----------------
static __device__ __forceinline__ void gload16(const void* g, void* l) {
    __builtin_amdgcn_global_load_lds(
        (const __attribute__((address_space(1))) unsigned int*)g,
        (__attribute__((address_space(3))) unsigned int*)l, 16, 0, 0);
}

// ---------------- MFMA GEMM: L = Xb @ Wb^T + b ----------------
__global__ __launch_bounds__(256) void gemm_mfma_k(
    const ushort_t* __restrict__ Xb, const ushort_t* __restrict__ Wb,
    const float* __restrict__ bias, float* __restrict__ L)
{
    __shared__ __align__(16) ushort_t As[128 * 32];   // [row][k], 64B/row
    __shared__ __align__(16) ushort_t Bs[128 * 32];

    const int tid  = threadIdx.x;
    const int lane = tid & 63;
    const int wv   = tid >> 6;          // 0..3
    const int wr   = (wv >> 1) * 64;
    const int wc   = (wv & 1) * 64;
    const int row0 = blockIdx.x * 128;
    const int col0 = blockIdx.y * 128;

    const int c0r = tid >> 2;
    const int c0k = (tid & 3) * 8;

    f32x4 acc[4][4] = {};

    const int rA = lane & 15;
    const int kb = (lane >> 4) * 8;

    for (int t = 0; t < 16; ++t) {
        const int k0 = t * 32;
        gload16(Xb + (size_t)(row0 + c0r) * FDIM + k0 + c0k,        &As[tid * 8]);
        gload16(Xb + (size_t)(row0 + 64 + c0r) * FDIM + k0 + c0k,   &As[2048 + tid * 8]);
        gload16(Wb + (size_t)(col0 + c0r) * FDIM + k0 + c0k,        &Bs[tid * 8]);
        gload16(Wb + (size_t)(col0 + 64 + c0r) * FDIM + k0 + c0k,   &Bs[2048 + tid * 8]);
        __syncthreads();

        bf16x8 af[4], bfr[4];
        #pragma unroll
        for (int mi = 0; mi < 4; ++mi)
            af[mi] = *(const bf16x8*)&As[(wr + mi * 16 + rA) * 32 + kb];
        #pragma unroll
        for (int ni = 0; ni < 4; ++ni)
            bfr[ni] = *(const bf16x8*)&Bs[(wc + ni * 16 + rA) * 32 + kb];

        #pragma unroll
        for (int mi = 0; mi < 4; ++mi)
            #pragma unroll
            for (int ni = 0; ni < 4; ++ni)
                acc[mi][ni] = __builtin_amdgcn_mfma_f32_16x16x32_bf16(
                    af[mi], bfr[ni], acc[mi][ni], 0, 0, 0);
        __syncthreads();
    }

    // C/D map: col = lane&15, row = (lane>>4)*4 + reg
    const int colb = col0 + wc + (lane & 15);
    const int rowb = row0 + wr + (lane >> 4) * 4;
    #pragma unroll
    for (int ni = 0; ni < 4; ++ni) {
        const int col = colb + ni * 16;
        const float bv = bias[col];
        #pragma unroll
        for (int mi = 0; mi < 4; ++mi) {
            const int row = rowb + mi * 16;
            #pragma unroll
            for (int j = 0; j < 4; ++j)
                L[(size_t)(row + j) * GE + col] = acc[mi][ni][j] + bv;
        }
    }
}

// ---------------- per-(n,g) epilogue, 1 row-g per wave ----------------
// Element mapping: lane owns e in { lane*4+0..3 (j=0..3), 256+lane (j=4) }.
// Vectorized: float4+dword loads/stores. Argmax tie-break compares global
// indices explicitly, so the mapping's non-monotonicity is harmless.
// L aliases the cb out region (read then overwritten by the owning wave).
__global__ __launch_bounds__(256) void vq_rows_k(
    float* __restrict__ Lcb,                 // logits in, cb out (same region)
    const float* __restrict__ gumbel,
    const float* __restrict__ entries,
    float* __restrict__ out,                 // d_out base (quantized at 0)
    float* __restrict__ acc_slots,           // nslots x 1280 floats in ws
    int nslots)
{
    __shared__ float redH[320], redS[320];

    const int tid  = threadIdx.x;
    const int lane = tid & 63;
    const int u    = blockIdx.x * 4 + (tid >> 6);   // 0..32767 row-g unit
    const int g    = u >> 14;                        // uniform per block
    const int n    = u & 16383;

    for (int e = tid; e < 320; e += 256) { redH[e] = 0.f; redS[e] = 0.f; }

    float* lrow = Lcb + (size_t)n * GE + g * EDIM;
    const float* grow = gumbel + ((size_t)n * 2 + g) * EDIM;

    // loads: e(j) = lane*4+j for j<4, 256+lane for j=4
    float l[5], gu[5];
    {
        const float4 lv = *(const float4*)(lrow + lane * 4);
        const float4 gv4 = *(const float4*)(grow + lane * 4);
        l[0] = lv.x; l[1] = lv.y; l[2] = lv.z; l[3] = lv.w;
        gu[0] = gv4.x; gu[1] = gv4.y; gu[2] = gv4.z; gu[3] = gv4.w;
        l[4]  = lrow[256 + lane];
        gu[4] = grow[256 + lane];
    }

    float t[5];
    #pragma unroll
    for (int j = 0; j < 5; ++j)
        t[j] = (l[j] + gu[j]) * 0.5f;   // (logits+gumbel)/TAU, TAU=2

    // local argmax with explicit index tie-break (first index wins)
    const int e4 = 256 + lane;
    float hv = l[0]; int hi = lane * 4;
    float gv = t[0]; int gi = lane * 4;
    #pragma unroll
    for (int j = 1; j < 5; ++j) {
        const int e = (j < 4) ? (lane * 4 + j) : e4;
        if (l[j] > hv || (l[j] == hv && e < hi)) { hv = l[j]; hi = e; }
        if (t[j] > gv || (t[j] == gv && e < gi)) { gv = t[j]; gi = e; }
    }
    #pragma unroll
    for (int off = 32; off > 0; off >>= 1) {
        float ov = __shfl_xor(hv, off); int oi = __shfl_xor(hi, off);
        if (ov > hv || (ov == hv && oi < hi)) { hv = ov; hi = oi; }
        float ov2 = __shfl_xor(gv, off); int oi2 = __shfl_xor(gi, off);
        if (ov2 > gv || (ov2 == gv && oi2 < gi)) { gv = ov2; gi = oi2; }
    }

    // softmax exps + sums (native v_exp: indices computed on raw values)
    float eh[5], eg[5];
    float sh = 0.f, sg = 0.f;
    #pragma unroll
    for (int j = 0; j < 5; ++j) {
        eh[j] = __expf(l[j] - hv);
        eg[j] = __expf(t[j] - gv);
        sh += eh[j]; sg += eg[j];
    }
    #pragma unroll
    for (int off = 32; off > 0; off >>= 1) {
        sh += __shfl_xor(sh, off);
        sg += __shfl_xor(sg, off);
    }
    const float ish = 1.0f / sh;
    const float isg = 1.0f / sg;

    // y_soft at gumbel argmax: gi uniform -> j-select + one shfl
    const int gj = (gi >= 256) ? 4 : (gi & 3);          // uniform
    const int gl = (gi >= 256) ? (gi - 256) : (gi >> 2); // uniform src lane
    float esel = eg[0];
    esel = (gj == 1) ? eg[1] : esel;
    esel = (gj == 2) ? eg[2] : esel;
    esel = (gj == 3) ? eg[3] : esel;
    esel = (gj == 4) ? eg[4] : esel;
    const float a_part = __shfl(esel, gl) * isg;
    const float yv = (1.0f - a_part) + a_part;   // straight-through value

    // cb write (overwrites logits slice in place), vectorized
    {
        float4 cv;
        cv.x = (lane * 4 + 0 == gi) ? yv : 0.0f;
        cv.y = (lane * 4 + 1 == gi) ? yv : 0.0f;
        cv.z = (lane * 4 + 2 == gi) ? yv : 0.0f;
        cv.w = (lane * 4 + 3 == gi) ? yv : 0.0f;
        *(float4*)(lrow + lane * 4) = cv;
        lrow[256 + lane] = (e4 == gi) ? yv : 0.0f;
    }

    // quantized write: yv * entries[g, gi, :], float4 + float2
    {
        const float* ent = entries + ((size_t)(g * EDIM + gi)) * DDIM;
        float* qrow = out + (size_t)n * 768 + g * DDIM;
        const float4 ev = *(const float4*)(ent + lane * 4);
        const float2 ev2 = *(const float2*)(ent + 256 + lane * 2);
        float4 qv; qv.x = yv * ev.x; qv.y = yv * ev.y;
        qv.z = yv * ev.z; qv.w = yv * ev.w;
        float2 qv2; qv2.x = yv * ev2.x; qv2.y = yv * ev2.y;
        *(float4*)(qrow + lane * 4) = qv;
        *(float2*)(qrow + 256 + lane * 2) = qv2;
    }

    // block-level reduction (all 4 waves same g), then one atomic per entry
    __syncthreads();
    #pragma unroll
    for (int j = 0; j < 4; ++j)
        atomicAdd(&redS[lane * 4 + j], eh[j] * ish);
    atomicAdd(&redS[256 + lane], eh[4] * ish);
    if (lane == 0) atomicAdd(&redH[hi], 1.0f);
    __syncthreads();
    float* slot = acc_slots + (size_t)(blockIdx.x & (nslots - 1)) * 1280;
    for (int e = tid; e < 320; e += 256) {
        atomicAdd(&slot[g * EDIM + e], redH[e]);
        atomicAdd(&slot[640 + g * EDIM + e], redS[e]);
    }
}

// ---------------- parallel slot reduction: 1280 threads ----------------
__global__ __launch_bounds__(256) void reduce_slots_k(
    const float* __restrict__ acc_slots, int nslots, float* __restrict__ red)
{
    const int idx = blockIdx.x * 256 + threadIdx.x;   // 0..1279
    if (idx >= 1280) return;
    float s = 0.f;
    for (int k = 0; k < nslots; ++k)
        s += acc_slots[(size_t)k * 1280 + idx];
    red[idx] = s;
}

// ---------------- perplexities ----------------
__global__ void vq_final_k(const float* __restrict__ red,
                           float* __restrict__ out)
{
    const int lane = threadIdx.x & 63;
    float code = 0.f, prob = 0.f;
    for (int g = 0; g < 2; ++g) {
        float shh = 0.f, sss = 0.f;
        #pragma unroll
        for (int j = 0; j < 5; ++j) {
            const int e = g * EDIM + lane + j * 64;
            const float ph = red[e] * (1.0f / 16384.0f);
            const float ps = red[640 + e] * (1.0f / 16384.0f);
            shh += ph * __logf(ph + 1e-7f);
            sss += ps * __logf(ps + 1e-7f);
        }
        #pragma unroll
        for (int off = 32; off > 0; off >>= 1) {
            shh += __shfl_xor(shh, off);
            sss += __shfl_xor(sss, off);
        }
        code += __expf(-shh);
        prob += __expf(-sss);
    }
    if (threadIdx.x == 0) {
        out[SCAL_OFF + 0] = code;
        out[SCAL_OFF + 1] = prob;
    }
}

extern "C" void kernel_launch(void* const* d_in, const int* in_sizes, int n_in,
                              void* d_out, int out_size, void* d_ws, size_t ws_size,
                              hipStream_t stream) {
    const float* x       = (const float*)d_in[0];
    const float* proj_w  = (const float*)d_in[1];
    const float* proj_b  = (const float*)d_in[2];
    const float* entries = (const float*)d_in[3];
    const float* gumbel  = (const float*)d_in[4];
    float* out = (float*)d_out;
    float* acc = (float*)d_ws;
    float* logits = out + CB_OFF;                  // logits staged in cb region
    ushort_t* Xb = (ushort_t*)(out + XB_OFF);      // bf16 X in quantized region
    ushort_t* Wb = (ushort_t*)(out + WB_OFF);      // bf16 W after it

    // 16 privatized slots + 1 reduced buffer: (16+1)*1280*4 = 87 KB
    const int nslots = (ws_size >= (size_t)17 * 1280 * 4) ? 16 : 1;
    float* red = acc + (size_t)nslots * 1280;
    const int nz = nslots * 1280;

    hipLaunchKernelGGL(vq_init_k, dim3((nz + 255) / 256), dim3(256), 0, stream,
                       acc, nz);
    hipLaunchKernelGGL(convert_bf16_k, dim3(4256), dim3(256), 0, stream,
                       x, proj_w, Xb, Wb);
    hipLaunchKernelGGL(gemm_mfma_k, dim3(NROWS / 128, GE / 128), dim3(256), 0, stream,
                       Xb, Wb, proj_b, logits);
    hipLaunchKernelGGL(vq_rows_k, dim3(8192), dim3(256), 0, stream,
                       logits, gumbel, entries, out, acc, nslots);
    hipLaunchKernelGGL(reduce_slots_k, dim3(5), dim3(256), 0, stream,
                       acc, nslots, red);
    hipLaunchKernelGGL(vq_final_k, dim3(1), dim3(64), 0, stream,
                       red, out);
}

// Round 7
// 87.429 us; speedup vs baseline: 1.3586x; 1.3586x over previous
//
#include <hip/hip_runtime.h>
#include <hip/hip_bf16.h>

typedef unsigned short ushort_t;
typedef __attribute__((ext_vector_type(8))) short bf16x8;
typedef __attribute__((ext_vector_type(4))) float f32x4;
typedef __attribute__((ext_vector_type(2))) float f32x2;

// Problem constants
#define NROWS 16384          // B*T
#define FDIM  512            // K
#define GE    640            // G*E
#define EDIM  320
#define DDIM  384
#define CB_OFF 12582912      // 16384*768
#define SCAL_OFF 23068672    // CB_OFF + 16384*640
// bf16 staging inside out[quantized region] (free until vq_rows)
#define XB_OFF 0
#define WB_OFF 4194304

// ws layout (floats): [0,640) hard_global | [640,1280) red_soft | [1280, +2048*320) slotS
#define WS_SLOT_OFF 1280
#define WS_NEED_FLOATS (1280 + 2048 * 320)

// ---------------- init accumulators ----------------
__global__ void vq_init_k(float* acc, int n) {
    int i = blockIdx.x * 256 + threadIdx.x;
    if (i < n) acc[i] = 0.0f;
}

// ---------------- fp32 -> bf16 convert (RNE) ----------------
static __device__ __forceinline__ unsigned f2bf(float f) {
    unsigned u = __float_as_uint(f);
    return (u + 0x7FFFu + ((u >> 16) & 1u)) >> 16;
}

__global__ __launch_bounds__(256) void convert_bf16_k(
    const float* __restrict__ X, const float* __restrict__ W,
    ushort_t* __restrict__ Xb, ushort_t* __restrict__ Wb)
{
    const size_t i = (size_t)blockIdx.x * 256 + threadIdx.x;
    const float4* src;
    ushort_t* dst;
    if (i < 1048576) {
        src = (const float4*)X + i * 2;
        dst = Xb + i * 8;
    } else {
        const size_t j = i - 1048576;
        src = (const float4*)W + j * 2;
        dst = Wb + j * 8;
    }
    const float4 v0 = src[0], v1 = src[1];
    uint4 o;
    o.x = f2bf(v0.x) | (f2bf(v0.y) << 16);
    o.y = f2bf(v0.z) | (f2bf(v0.w) << 16);
    o.z = f2bf(v1.x) | (f2bf(v1.y) << 16);
    o.w = f2bf(v1.z) | (f2bf(v1.w) << 16);
    *(uint4*)dst = o;
}

// ---------------- async global->LDS helper ----------------
static __device__ __forceinline__ void gload16(const void* g, void* l) {
    __builtin_amdgcn_global_load_lds(
        (const __attribute__((address_space(1))) unsigned int*)g,
        (__attribute__((address_space(3))) unsigned int*)l, 16, 0, 0);
}

// ---------------- nontemporal store helpers ----------------
static __device__ __forceinline__ void nts4(float* p, f32x4 v) {
    __builtin_nontemporal_store(v, (f32x4*)p);
}
static __device__ __forceinline__ void nts2(float* p, f32x2 v) {
    __builtin_nontemporal_store(v, (f32x2*)p);
}
static __device__ __forceinline__ void nts1(float* p, float v) {
    __builtin_nontemporal_store(v, p);
}

// ---------------- MFMA GEMM: L = Xb @ Wb^T + b ----------------
__global__ __launch_bounds__(256) void gemm_mfma_k(
    const ushort_t* __restrict__ Xb, const ushort_t* __restrict__ Wb,
    const float* __restrict__ bias, float* __restrict__ L)
{
    __shared__ __align__(16) ushort_t As[128 * 32];   // [row][k], 64B/row
    __shared__ __align__(16) ushort_t Bs[128 * 32];

    const int tid  = threadIdx.x;
    const int lane = tid & 63;
    const int wv   = tid >> 6;
    const int wr   = (wv >> 1) * 64;
    const int wc   = (wv & 1) * 64;
    const int row0 = blockIdx.x * 128;
    const int col0 = blockIdx.y * 128;

    const int c0r = tid >> 2;
    const int c0k = (tid & 3) * 8;

    f32x4 acc[4][4] = {};

    const int rA = lane & 15;
    const int kb = (lane >> 4) * 8;

    for (int t = 0; t < 16; ++t) {
        const int k0 = t * 32;
        gload16(Xb + (size_t)(row0 + c0r) * FDIM + k0 + c0k,        &As[tid * 8]);
        gload16(Xb + (size_t)(row0 + 64 + c0r) * FDIM + k0 + c0k,   &As[2048 + tid * 8]);
        gload16(Wb + (size_t)(col0 + c0r) * FDIM + k0 + c0k,        &Bs[tid * 8]);
        gload16(Wb + (size_t)(col0 + 64 + c0r) * FDIM + k0 + c0k,   &Bs[2048 + tid * 8]);
        __syncthreads();

        bf16x8 af[4], bfr[4];
        #pragma unroll
        for (int mi = 0; mi < 4; ++mi)
            af[mi] = *(const bf16x8*)&As[(wr + mi * 16 + rA) * 32 + kb];
        #pragma unroll
        for (int ni = 0; ni < 4; ++ni)
            bfr[ni] = *(const bf16x8*)&Bs[(wc + ni * 16 + rA) * 32 + kb];

        #pragma unroll
        for (int mi = 0; mi < 4; ++mi)
            #pragma unroll
            for (int ni = 0; ni < 4; ++ni)
                acc[mi][ni] = __builtin_amdgcn_mfma_f32_16x16x32_bf16(
                    af[mi], bfr[ni], acc[mi][ni], 0, 0, 0);
        __syncthreads();
    }

    // C/D map: col = lane&15, row = (lane>>4)*4 + reg
    const int colb = col0 + wc + (lane & 15);
    const int rowb = row0 + wr + (lane >> 4) * 4;
    #pragma unroll
    for (int ni = 0; ni < 4; ++ni) {
        const int col = colb + ni * 16;
        const float bv = bias[col];
        #pragma unroll
        for (int mi = 0; mi < 4; ++mi) {
            const int row = rowb + mi * 16;
            #pragma unroll
            for (int j = 0; j < 4; ++j)
                L[(size_t)(row + j) * GE + col] = acc[mi][ni][j] + bv;
        }
    }
}

// ---------------- per-(n,g) epilogue ----------------
// 2048 blocks x 4 waves, 4 rows per wave (same g per block).
// Element map: lane owns e in { lane*4+0..3, 256+lane }.
// cb/quantized written with NONTEMPORAL stores (bypass L2).
// Soft-prob partials: plain stores to private slot (no atomics) when ws fits.
__global__ __launch_bounds__(256) void vq_rows_k(
    float* __restrict__ Lcb,                 // logits in, cb out (same region)
    const float* __restrict__ gumbel,
    const float* __restrict__ entries,
    float* __restrict__ out,                 // d_out base (quantized at 0)
    float* __restrict__ hard_global,         // ws[0..640)
    float* __restrict__ red_soft,            // ws[640..1280)
    float* __restrict__ slotS,               // ws[1280..], [2048][320]
    int use_slots)
{
    __shared__ float redS[4][320];
    __shared__ int hIdxA[16];

    const int tid  = threadIdx.x;
    const int lane = tid & 63;
    const int wv   = tid >> 6;
    const int w    = blockIdx.x * 4 + wv;    // 0..8191
    const int g    = w >> 12;                 // uniform per block
    const int nb   = w & 4095;

    float racc[5] = {0.f, 0.f, 0.f, 0.f, 0.f};
    int hrec[4];

    float l[5], gu[5], l2[5], gu2[5];
    {
        float* lrow = Lcb + (size_t)nb * GE + g * EDIM;
        const float* grow = gumbel + ((size_t)nb * 2 + g) * EDIM;
        f32x4 lv = *(const f32x4*)(lrow + lane * 4);
        f32x4 gv4 = *(const f32x4*)(grow + lane * 4);
        l[0] = lv[0]; l[1] = lv[1]; l[2] = lv[2]; l[3] = lv[3];
        gu[0] = gv4[0]; gu[1] = gv4[1]; gu[2] = gv4[2]; gu[3] = gv4[3];
        l[4]  = lrow[256 + lane];
        gu[4] = grow[256 + lane];
    }

    #pragma unroll
    for (int i = 0; i < 4; ++i) {
        const int n = nb + (i << 12);
        if (i < 3) {
            const int n2 = nb + ((i + 1) << 12);
            const float* lrow2 = Lcb + (size_t)n2 * GE + g * EDIM;
            const float* grow2 = gumbel + ((size_t)n2 * 2 + g) * EDIM;
            f32x4 lv = *(const f32x4*)(lrow2 + lane * 4);
            f32x4 gv4 = *(const f32x4*)(grow2 + lane * 4);
            l2[0] = lv[0]; l2[1] = lv[1]; l2[2] = lv[2]; l2[3] = lv[3];
            gu2[0] = gv4[0]; gu2[1] = gv4[1]; gu2[2] = gv4[2]; gu2[3] = gv4[3];
            l2[4]  = lrow2[256 + lane];
            gu2[4] = grow2[256 + lane];
        }

        float t[5];
        #pragma unroll
        for (int j = 0; j < 5; ++j)
            t[j] = (l[j] + gu[j]) * 0.5f;   // (logits+gumbel)/TAU, TAU=2

        // local argmax with explicit index tie-break (first index wins)
        const int e4 = 256 + lane;
        float hv = l[0]; int hi = lane * 4;
        float gv = t[0]; int gi = lane * 4;
        #pragma unroll
        for (int j = 1; j < 5; ++j) {
            const int e = (j < 4) ? (lane * 4 + j) : e4;
            if (l[j] > hv || (l[j] == hv && e < hi)) { hv = l[j]; hi = e; }
            if (t[j] > gv || (t[j] == gv && e < gi)) { gv = t[j]; gi = e; }
        }
        #pragma unroll
        for (int off = 32; off > 0; off >>= 1) {
            float ov = __shfl_xor(hv, off); int oi = __shfl_xor(hi, off);
            if (ov > hv || (ov == hv && oi < hi)) { hv = ov; hi = oi; }
            float ov2 = __shfl_xor(gv, off); int oi2 = __shfl_xor(gi, off);
            if (ov2 > gv || (ov2 == gv && oi2 < gi)) { gv = ov2; gi = oi2; }
        }
        hrec[i] = hi;   // wave-uniform

        // softmax exps + sums (native v_exp; argmax used raw values)
        float eh[5], eg[5];
        float sh = 0.f, sg = 0.f;
        #pragma unroll
        for (int j = 0; j < 5; ++j) {
            eh[j] = __expf(l[j] - hv);
            eg[j] = __expf(t[j] - gv);
            sh += eh[j]; sg += eg[j];
        }
        #pragma unroll
        for (int off = 32; off > 0; off >>= 1) {
            sh += __shfl_xor(sh, off);
            sg += __shfl_xor(sg, off);
        }
        const float ish = 1.0f / sh;
        const float isg = 1.0f / sg;

        // y_soft at gumbel argmax: gi uniform -> j-select + one shfl
        const int gj = (gi >= 256) ? 4 : (gi & 3);
        const int gl = (gi >= 256) ? (gi - 256) : (gi >> 2);
        float esel = eg[0];
        esel = (gj == 1) ? eg[1] : esel;
        esel = (gj == 2) ? eg[2] : esel;
        esel = (gj == 3) ? eg[3] : esel;
        esel = (gj == 4) ? eg[4] : esel;
        const float a_part = __shfl(esel, gl) * isg;
        const float yv = (1.0f - a_part) + a_part;   // straight-through value

        // accumulate soft probs
        #pragma unroll
        for (int j = 0; j < 5; ++j) racc[j] += eh[j] * ish;

        // cb write (overwrites logits slice in place), nontemporal
        {
            float* lrow = Lcb + (size_t)n * GE + g * EDIM;
            f32x4 cv;
            cv[0] = (lane * 4 + 0 == gi) ? yv : 0.0f;
            cv[1] = (lane * 4 + 1 == gi) ? yv : 0.0f;
            cv[2] = (lane * 4 + 2 == gi) ? yv : 0.0f;
            cv[3] = (lane * 4 + 3 == gi) ? yv : 0.0f;
            nts4(lrow + lane * 4, cv);
            nts1(lrow + 256 + lane, (e4 == gi) ? yv : 0.0f);
        }

        // quantized write: yv * entries[g, gi, :], nontemporal
        {
            const float* ent = entries + ((size_t)(g * EDIM + gi)) * DDIM;
            float* qrow = out + (size_t)n * 768 + g * DDIM;
            const f32x4 ev = *(const f32x4*)(ent + lane * 4);
            const f32x2 ev2 = *(const f32x2*)(ent + 256 + lane * 2);
            f32x4 qv; qv[0] = yv * ev[0]; qv[1] = yv * ev[1];
            qv[2] = yv * ev[2]; qv[3] = yv * ev[3];
            f32x2 qv2; qv2[0] = yv * ev2[0]; qv2[1] = yv * ev2[1];
            nts4(qrow + lane * 4, qv);
            nts2(qrow + 256 + lane * 2, qv2);
        }

        #pragma unroll
        for (int j = 0; j < 5; ++j) { l[j] = l2[j]; gu[j] = gu2[j]; }
    }

    // cross-wave reduction via plain LDS writes (no atomics)
    {
        f32x4 rv; rv[0] = racc[0]; rv[1] = racc[1]; rv[2] = racc[2]; rv[3] = racc[3];
        *(f32x4*)&redS[wv][lane * 4] = rv;
        redS[wv][256 + lane] = racc[4];
        if (lane == 0) {
            #pragma unroll
            for (int i = 0; i < 4; ++i) hIdxA[wv * 4 + i] = hrec[i];
        }
    }
    __syncthreads();

    for (int e = tid; e < 320; e += 256) {
        const float s = redS[0][e] + redS[1][e] + redS[2][e] + redS[3][e];
        int cnt = 0;
        #pragma unroll
        for (int k = 0; k < 16; ++k) cnt += (hIdxA[k] == e) ? 1 : 0;
        if (use_slots) slotS[(size_t)blockIdx.x * 320 + e] = s;
        else atomicAdd(&red_soft[g * EDIM + e], s);
        if (cnt > 0) atomicAdd(&hard_global[g * EDIM + e], (float)cnt);
    }
}

// ---------------- slot reduction: one block per (g,e) ----------------
__global__ __launch_bounds__(64) void reduce_soft_k(
    const float* __restrict__ slotS, float* __restrict__ red_soft)
{
    const int g = blockIdx.x / EDIM;
    const int e = blockIdx.x % EDIM;
    const int lane = threadIdx.x;
    float s = 0.f;
    #pragma unroll 4
    for (int k = lane; k < 1024; k += 64)
        s += slotS[(size_t)(g * 1024 + k) * 320 + e];
    #pragma unroll
    for (int off = 32; off > 0; off >>= 1) s += __shfl_xor(s, off);
    if (lane == 0) red_soft[g * EDIM + e] = s;
}

// ---------------- perplexities ----------------
__global__ void vq_final_k(const float* __restrict__ hard_global,
                           const float* __restrict__ red_soft,
                           float* __restrict__ out)
{
    const int lane = threadIdx.x & 63;
    float code = 0.f, prob = 0.f;
    for (int g = 0; g < 2; ++g) {
        float shh = 0.f, sss = 0.f;
        #pragma unroll
        for (int j = 0; j < 5; ++j) {
            const int e = g * EDIM + lane + j * 64;
            const float ph = hard_global[e] * (1.0f / 16384.0f);
            const float ps = red_soft[e] * (1.0f / 16384.0f);
            shh += ph * __logf(ph + 1e-7f);
            sss += ps * __logf(ps + 1e-7f);
        }
        #pragma unroll
        for (int off = 32; off > 0; off >>= 1) {
            shh += __shfl_xor(shh, off);
            sss += __shfl_xor(sss, off);
        }
        code += __expf(-shh);
        prob += __expf(-sss);
    }
    if (threadIdx.x == 0) {
        out[SCAL_OFF + 0] = code;
        out[SCAL_OFF + 1] = prob;
    }
}

extern "C" void kernel_launch(void* const* d_in, const int* in_sizes, int n_in,
                              void* d_out, int out_size, void* d_ws, size_t ws_size,
                              hipStream_t stream) {
    const float* x       = (const float*)d_in[0];
    const float* proj_w  = (const float*)d_in[1];
    const float* proj_b  = (const float*)d_in[2];
    const float* entries = (const float*)d_in[3];
    const float* gumbel  = (const float*)d_in[4];
    float* out = (float*)d_out;
    float* ws  = (float*)d_ws;
    float* logits = out + CB_OFF;
    ushort_t* Xb = (ushort_t*)(out + XB_OFF);
    ushort_t* Wb = (ushort_t*)(out + WB_OFF);

    float* hard_global = ws;
    float* red_soft    = ws + 640;
    float* slotS       = ws + WS_SLOT_OFF;
    const int use_slots = (ws_size >= (size_t)WS_NEED_FLOATS * 4) ? 1 : 0;

    hipLaunchKernelGGL(vq_init_k, dim3(5), dim3(256), 0, stream, ws, 1280);
    hipLaunchKernelGGL(convert_bf16_k, dim3(4256), dim3(256), 0, stream,
                       x, proj_w, Xb, Wb);
    hipLaunchKernelGGL(gemm_mfma_k, dim3(NROWS / 128, GE / 128), dim3(256), 0, stream,
                       Xb, Wb, proj_b, logits);
    hipLaunchKernelGGL(vq_rows_k, dim3(2048), dim3(256), 0, stream,
                       logits, gumbel, entries, out,
                       hard_global, red_soft, slotS, use_slots);
    if (use_slots)
        hipLaunchKernelGGL(reduce_soft_k, dim3(640), dim3(64), 0, stream,
                           slotS, red_soft);
    hipLaunchKernelGGL(vq_final_k, dim3(1), dim3(64), 0, stream,
                       hard_global, red_soft, out);
}